// Round 5
// baseline (10803.985 us; speedup 1.0000x reference)
//
#include <hip/hip_runtime.h>
#include <stdint.h>

// ---------------------------------------------------------------------------
// 2-layer LSTM (T=256, B=256, F=128, H=1024) for MI355X (gfx950).
// R5: h-sharing is intra-mi-group (wg&7). Per-group 32-WG barriers (relaxed,
// same-XCD L2 atomics), NO agent fences in fast path: stores drain to L2 via
// __syncthreads vmcnt(0); readers use agent-scope relaxed atomic loads (sc1,
// bypass stale vL1, hit own-XCD L2). LDS h-slab deleted - MFMA A-fragments
// load directly from global. Per-launch probe validates co-XCD mapping; on
// mismatch fall back to agent release/acquire fences (R4 behavior).
// xw GEMM restored to global_load_lds width-16 (m97 ladder).
// ---------------------------------------------------------------------------

typedef __bf16 bf16x8 __attribute__((ext_vector_type(8)));
typedef float  f32x4  __attribute__((ext_vector_type(4)));
typedef unsigned short ushort8v __attribute__((ext_vector_type(8)));
typedef unsigned short ushort4v __attribute__((ext_vector_type(4)));
typedef unsigned int   uint4v   __attribute__((ext_vector_type(4)));
typedef __attribute__((address_space(1))) unsigned int as1_u32;
typedef __attribute__((address_space(3))) unsigned int as3_u32;

#define T_STEPS 256
#define BATCH   256
#define HDIM    1024
#define GDIM    4096
#define FDIM    128

static __device__ __forceinline__ float bf2f(unsigned short u) {
  union { unsigned int i; float f; } v; v.i = ((unsigned int)u) << 16; return v.f;
}
static __device__ __forceinline__ unsigned short f2bf(float f) {
  return __builtin_bit_cast(unsigned short, (__bf16)f);
}
static __device__ __forceinline__ float sigm(float x) { return 1.f / (1.f + __expf(-x)); }
static __device__ __forceinline__ float tanh_f(float x) { return 2.f / (1.f + __expf(-2.f * x)) - 1.f; }

// 16B fragment load that bypasses vL1 (sc1) and reads the XCD L2.
static __device__ __forceinline__ bf16x8 load_frag_l2(const unsigned short* p) {
  union { unsigned long long q[2]; bf16x8 v; } u;
  u.q[0] = __hip_atomic_load((const unsigned long long*)p,       __ATOMIC_RELAXED, __HIP_MEMORY_SCOPE_AGENT);
  u.q[1] = __hip_atomic_load((const unsigned long long*)(p + 4), __ATOMIC_RELAXED, __HIP_MEMORY_SCOPE_AGENT);
  return u.v;
}

__global__ void conv_bf16(const float* __restrict__ s, unsigned short* __restrict__ d, int n) {
  int i = blockIdx.x * 256 + threadIdx.x;
  if (i < n) d[i] = f2bf(s[i]);
}

__global__ void diag_kernel(float* out, int n, float v) {
  int i = blockIdx.x * 256 + threadIdx.x;
  if (i < n) out[i] = v;
}

// ---------------- per-group (32-WG, same mi) monotonic barrier ---------------
// gbar: this group's 256B region. [0]=arrival count, [32](+128B)=generation.
// heavy=true adds agent release/acquire fences (cross-XCD-safe fallback).
__device__ __forceinline__ void grp_barrier(unsigned int* gbar, unsigned int target, bool heavy) {
  __syncthreads();   // drains vmcnt(0): all WG stores visible at L2
  if (threadIdx.x == 0) {
    if (heavy) __builtin_amdgcn_fence(__ATOMIC_RELEASE, "agent");
    unsigned int my = __hip_atomic_fetch_add(&gbar[0], 1u, __ATOMIC_RELAXED, __HIP_MEMORY_SCOPE_AGENT);
    if ((my & 31u) == 31u)
      __hip_atomic_fetch_add(&gbar[32], 1u, __ATOMIC_RELAXED, __HIP_MEMORY_SCOPE_AGENT);
    for (unsigned int it = 0; it < (1u << 14); ++it) {
      unsigned int g = __hip_atomic_load(&gbar[32], __ATOMIC_RELAXED, __HIP_MEMORY_SCOPE_AGENT);
      if ((int)(g - target) >= 0) break;
      __builtin_amdgcn_s_sleep(1);
    }
    if (heavy) __builtin_amdgcn_fence(__ATOMIC_ACQUIRE, "agent");
  }
  __syncthreads();
}

// --------------------------- gemm_bt: C = A @ B^T ---------------------------
// A: (M,K) bf16 row-major. B: (4096,K) bf16. global_load_lds width-16 staging.
// Output alt layout xw[(t_local*4096 + n)*256 + b], m = t_local*256 + b.
__global__ __launch_bounds__(256) void gemm_bt_xw(
    const unsigned short* __restrict__ A,
    const unsigned short* __restrict__ B,
    unsigned short* __restrict__ xw,
    int K)
{
  const int tid = threadIdx.x, lane = tid & 63, w = tid >> 6;
  const int m0 = blockIdx.x * 128;
  const int n0 = blockIdx.y * 128;
  __shared__ unsigned short As[128 * 64];
  __shared__ unsigned short Bs[128 * 64];
  const int mrow0 = (w & 1) * 64, ncol0 = (w >> 1) * 64;
  const int quad = lane >> 4;

  f32x4 acc[4][4];
  #pragma unroll
  for (int i = 0; i < 4; ++i)
    #pragma unroll
    for (int j = 0; j < 4; ++j) acc[i][j] = f32x4{0.f, 0.f, 0.f, 0.f};

  const int kiter = K >> 6;
  for (int ki = 0; ki < kiter; ++ki) {
    const int k0 = ki * 64;
    __syncthreads();
    #pragma unroll
    for (int i = 0; i < 4; ++i) {
      int obase = (w * 4 + i) * 1024;          // wave-uniform LDS byte base
      int o = obase + lane * 16;               // this lane's global slot
      int row = o >> 7; int kb = o & 127;
      const char* ga = (const char*)A + ((size_t)(m0 + row) * K + k0) * 2 + kb;
      const char* gb = (const char*)B + ((size_t)(n0 + row) * K + k0) * 2 + kb;
      __builtin_amdgcn_global_load_lds((const as1_u32*)ga, (as3_u32*)((char*)As + obase), 16, 0, 0);
      __builtin_amdgcn_global_load_lds((const as1_u32*)gb, (as3_u32*)((char*)Bs + obase), 16, 0, 0);
    }
    __syncthreads();
    #pragma unroll
    for (int kk = 0; kk < 2; ++kk) {
      bf16x8 af[4], bfr[4];
      #pragma unroll
      for (int mt = 0; mt < 4; ++mt)
        af[mt] = *(const bf16x8*)(As + (mrow0 + mt * 16 + (lane & 15)) * 64 + kk * 32 + quad * 8);
      #pragma unroll
      for (int nt = 0; nt < 4; ++nt)
        bfr[nt] = *(const bf16x8*)(Bs + (ncol0 + nt * 16 + (lane & 15)) * 64 + kk * 32 + quad * 8);
      #pragma unroll
      for (int mt = 0; mt < 4; ++mt)
        #pragma unroll
        for (int nt = 0; nt < 4; ++nt)
          acc[mt][nt] = __builtin_amdgcn_mfma_f32_16x16x32_bf16(af[mt], bfr[nt], acc[mt][nt], 0, 0, 0);
    }
  }
  #pragma unroll
  for (int mt = 0; mt < 4; ++mt) {
    int m = m0 + mrow0 + mt * 16 + quad * 4;
    int tl = m >> 8, b = m & 255;
    #pragma unroll
    for (int nt = 0; nt < 4; ++nt) {
      int col = n0 + ncol0 + nt * 16 + (lane & 15);
      ushort4v v;
      v.x = f2bf(acc[mt][nt][0]); v.y = f2bf(acc[mt][nt][1]);
      v.z = f2bf(acc[mt][nt][2]); v.w = f2bf(acc[mt][nt][3]);
      *(ushort4v*)(xw + ((size_t)tl * GDIM + col) * BATCH + b) = v;
    }
  }
}

// ---------------- probe: validate intra-XCD visibility for this group --------
// Plain-store token -> FAST barrier -> sc1-read all 32 members. If any member's
// token is stale (group not co-XCD), use heavy fences for the whole launch.
__device__ __forceinline__ bool probe_fast(unsigned int* probe, unsigned int* gbar,
                                           unsigned int salt, unsigned int target,
                                           unsigned int* flagLds) {
  const int wg = blockIdx.x, mi = wg & 7;
  if (threadIdx.x == 0) probe[wg * 32] = salt ^ (unsigned int)wg;
  grp_barrier(gbar, target, false);
  if (threadIdx.x == 0) {
    unsigned int bad = 0;
    for (int k = 0; k < 32; ++k) {
      int member = mi + 8 * k;
      unsigned int v = __hip_atomic_load(&probe[member * 32], __ATOMIC_RELAXED, __HIP_MEMORY_SCOPE_AGENT);
      if (v != (salt ^ (unsigned int)member)) bad = 1;
    }
    *flagLds = bad;
  }
  __syncthreads();
  return (*flagLds == 0);
}

// --------------------------- layer 0: fused persistent chunk -----------------
// 256 WGs x 256 thr, 1/CU. WG (mi=wg&7, ni=wg>>3): rows [32mi,+32), cols [32ni,+32).
// Wave g = gate g; W_hh0 + W_ih0 B-fragments resident in VGPRs.
// h A-fragments loaded straight from global (sc1 -> own-XCD L2). No LDS slab.
__global__ __launch_bounds__(256, 1) void lstm_layer0_kernel(
    const unsigned short* __restrict__ xbf,  // (T,B,F) bf16
    const float* __restrict__ Wih,           // (4096,128) fp32
    const float* __restrict__ Whh,           // (4096,1024) fp32
    const float* __restrict__ bih,
    const float* __restrict__ bhh,
    unsigned short* __restrict__ slab,       // (ch_len+1, B, H) bf16
    float* __restrict__ cstate,              // (B,H) fp32
    int t0, int ch_len, unsigned int gen_base,
    float* __restrict__ dout_h,
    float* __restrict__ dout_c,
    unsigned int* __restrict__ bar,
    unsigned int* __restrict__ probe)
{
  const int tid = threadIdx.x, lane = tid & 63, wv = tid >> 6;
  const int quad = lane >> 4;
  const int wg = blockIdx.x;
  const int mi = wg & 7, ni = wg >> 3;
  const int r0 = mi * 32, hc0 = ni * 32;
  unsigned int* gbar = bar + mi * 64;   // 256B per group

  __shared__ float gbuf[4][32][36];
  __shared__ unsigned int flagLds;

  bf16x8 whh[2][32];
  #pragma unroll
  for (int nt = 0; nt < 2; ++nt) {
    const float* wrow = Whh + (size_t)(wv * HDIM + hc0 + nt * 16 + (lane & 15)) * HDIM + quad * 8;
    #pragma unroll
    for (int kk = 0; kk < 32; ++kk) {
      f32x4 f0 = *(const f32x4*)(wrow + kk * 32);
      f32x4 f1 = *(const f32x4*)(wrow + kk * 32 + 4);
      bf16x8 r;
      r[0] = (__bf16)f0[0]; r[1] = (__bf16)f0[1]; r[2] = (__bf16)f0[2]; r[3] = (__bf16)f0[3];
      r[4] = (__bf16)f1[0]; r[5] = (__bf16)f1[1]; r[6] = (__bf16)f1[2]; r[7] = (__bf16)f1[3];
      whh[nt][kk] = r;
    }
  }
  bf16x8 wih[2][4];
  #pragma unroll
  for (int nt = 0; nt < 2; ++nt) {
    const float* wrow = Wih + (size_t)(wv * HDIM + hc0 + nt * 16 + (lane & 15)) * FDIM + quad * 8;
    #pragma unroll
    for (int kk = 0; kk < 4; ++kk) {
      f32x4 f0 = *(const f32x4*)(wrow + kk * 32);
      f32x4 f1 = *(const f32x4*)(wrow + kk * 32 + 4);
      bf16x8 r;
      r[0] = (__bf16)f0[0]; r[1] = (__bf16)f0[1]; r[2] = (__bf16)f0[2]; r[3] = (__bf16)f0[3];
      r[4] = (__bf16)f1[0]; r[5] = (__bf16)f1[1]; r[6] = (__bf16)f1[2]; r[7] = (__bf16)f1[3];
      wih[nt][kk] = r;
    }
  }

  const int hcl = tid & 31, rg = tid >> 5;
  float bias[4];
  #pragma unroll
  for (int g = 0; g < 4; ++g)
    bias[g] = bih[g * HDIM + hc0 + hcl] + bhh[g * HDIM + hc0 + hcl];

  float c[4];
  #pragma unroll
  for (int r = 0; r < 4; ++r)
    c[r] = (t0 == 0) ? 0.f : cstate[(size_t)(r0 + rg * 4 + r) * HDIM + hc0 + hcl];

  unsigned int salt = 0x9E3779B9u ^ (gen_base * 2654435761u);
  bool fast = probe_fast(probe, gbar, salt, gen_base + 1u, &flagLds);

  const int tend = t0 + ch_len;
  #pragma unroll 1
  for (int t = t0; t < tend; ++t) {
    f32x4 acc[2][2];
    #pragma unroll
    for (int mt = 0; mt < 2; ++mt)
      #pragma unroll
      for (int nt = 0; nt < 2; ++nt) acc[mt][nt] = f32x4{0.f, 0.f, 0.f, 0.f};

    // x projection (K=128), read-only -> plain loads
    #pragma unroll
    for (int j = 0; j < 4; ++j) {
      bf16x8 af[2];
      #pragma unroll
      for (int mt = 0; mt < 2; ++mt)
        af[mt] = *(const bf16x8*)(xbf + (size_t)(t * BATCH + r0 + mt * 16 + (lane & 15)) * FDIM + j * 32 + quad * 8);
      #pragma unroll
      for (int mt = 0; mt < 2; ++mt)
        #pragma unroll
        for (int nt = 0; nt < 2; ++nt)
          acc[mt][nt] = __builtin_amdgcn_mfma_f32_16x16x32_bf16(af[mt], wih[nt][j], acc[mt][nt], 0, 0, 0);
    }

    if (t > 0) {
      const unsigned short* Aprev = slab + (size_t)(t - t0) * (BATCH * HDIM);
      const unsigned short* hb0 = Aprev + (size_t)(r0 + (lane & 15)) * HDIM + quad * 8;
      const unsigned short* hb1 = hb0 + 16 * HDIM;
      #pragma unroll
      for (int j = 0; j < 32; ++j) {
        bf16x8 a0 = load_frag_l2(hb0 + j * 32);
        bf16x8 a1 = load_frag_l2(hb1 + j * 32);
        acc[0][0] = __builtin_amdgcn_mfma_f32_16x16x32_bf16(a0, whh[0][j], acc[0][0], 0, 0, 0);
        acc[0][1] = __builtin_amdgcn_mfma_f32_16x16x32_bf16(a0, whh[1][j], acc[0][1], 0, 0, 0);
        acc[1][0] = __builtin_amdgcn_mfma_f32_16x16x32_bf16(a1, whh[0][j], acc[1][0], 0, 0, 0);
        acc[1][1] = __builtin_amdgcn_mfma_f32_16x16x32_bf16(a1, whh[1][j], acc[1][1], 0, 0, 0);
      }
    }

    __syncthreads();
    #pragma unroll
    for (int mt = 0; mt < 2; ++mt)
      #pragma unroll
      for (int nt = 0; nt < 2; ++nt) {
        int hl = nt * 16 + (lane & 15);
        int rq = mt * 16 + quad * 4;
        *(f32x4*)&gbuf[wv][hl][rq] = acc[mt][nt];
      }
    __syncthreads();

    unsigned short* hdst = slab + (size_t)(t - t0 + 1) * (BATCH * HDIM);
    unsigned short* hdst0 = slab;
    #pragma unroll
    for (int r = 0; r < 4; ++r) {
      int row = rg * 4 + r;
      float gi = gbuf[0][hcl][row] + bias[0];
      float gf = gbuf[1][hcl][row] + bias[1];
      float gg = gbuf[2][hcl][row] + bias[2];
      float go = gbuf[3][hcl][row] + bias[3];
      float iv = sigm(gi), fv = sigm(gf), gv = tanh_f(gg), ov = sigm(go);
      float cn = fv * c[r] + iv * gv;
      c[r] = cn;
      float hv = ov * tanh_f(cn);
      int gidx = (r0 + row) * HDIM + hc0 + hcl;
      unsigned short hb = f2bf(hv);
      hdst[gidx] = hb;
      if (t == tend - 1) { hdst0[gidx] = hb; cstate[gidx] = cn; }
      if (t == T_STEPS - 1) { dout_h[gidx] = hv; dout_c[gidx] = cn; }
    }

    if (t != tend - 1)
      grp_barrier(gbar, gen_base + 2u + (unsigned int)(t - t0), !fast);
  }
}

// --------------------------- layer 1: persistent chunk ----------------------
__global__ __launch_bounds__(256, 1) void lstm_layer1_kernel(
    const unsigned short* __restrict__ xw,   // (ch_len, 4096, 256) bf16
    const float* __restrict__ Whh,
    const float* __restrict__ bih,
    const float* __restrict__ bhh,
    unsigned short* __restrict__ hpp,        // 2-slot ping-pong
    float* __restrict__ cstate,
    int t0, int ch_len, unsigned int gen_base,
    unsigned short* __restrict__ h1t0,
    float* __restrict__ dout_h,
    float* __restrict__ dout_c,
    unsigned int* __restrict__ bar,
    unsigned int* __restrict__ probe)
{
  const int tid = threadIdx.x, lane = tid & 63, wv = tid >> 6;
  const int quad = lane >> 4;
  const int wg = blockIdx.x;
  const int mi = wg & 7, ni = wg >> 3;
  const int r0 = mi * 32, hc0 = ni * 32;
  unsigned int* gbar = bar + mi * 64;

  __shared__ float gbuf[4][32][36];
  __shared__ unsigned int flagLds;

  bf16x8 whh[2][32];
  #pragma unroll
  for (int nt = 0; nt < 2; ++nt) {
    const float* wrow = Whh + (size_t)(wv * HDIM + hc0 + nt * 16 + (lane & 15)) * HDIM + quad * 8;
    #pragma unroll
    for (int kk = 0; kk < 32; ++kk) {
      f32x4 f0 = *(const f32x4*)(wrow + kk * 32);
      f32x4 f1 = *(const f32x4*)(wrow + kk * 32 + 4);
      bf16x8 r;
      r[0] = (__bf16)f0[0]; r[1] = (__bf16)f0[1]; r[2] = (__bf16)f0[2]; r[3] = (__bf16)f0[3];
      r[4] = (__bf16)f1[0]; r[5] = (__bf16)f1[1]; r[6] = (__bf16)f1[2]; r[7] = (__bf16)f1[3];
      whh[nt][kk] = r;
    }
  }

  const int hcl = tid & 31, rg = tid >> 5;
  float bias[4];
  #pragma unroll
  for (int g = 0; g < 4; ++g)
    bias[g] = bih[g * HDIM + hc0 + hcl] + bhh[g * HDIM + hc0 + hcl];

  float c[4];
  #pragma unroll
  for (int r = 0; r < 4; ++r)
    c[r] = (t0 == 0) ? 0.f : cstate[(size_t)(r0 + rg * 4 + r) * HDIM + hc0 + hcl];

  unsigned int salt = 0xB5297A4Du ^ (gen_base * 2654435761u);
  bool fast = probe_fast(probe, gbar, salt, gen_base + 1u, &flagLds);

  const int tend = t0 + ch_len;
  #pragma unroll 1
  for (int t = t0; t < tend; ++t) {
    // hoisted xw loads (addresses differ every step -> no vL1 staleness)
    float xwv[4][4];
    #pragma unroll
    for (int g = 0; g < 4; ++g) {
      const unsigned short* xp =
          xw + ((size_t)(t - t0) * GDIM + g * HDIM + hc0 + hcl) * BATCH + r0 + rg * 4;
      ushort4v u = *(const ushort4v*)xp;
      xwv[g][0] = bf2f(u.x); xwv[g][1] = bf2f(u.y);
      xwv[g][2] = bf2f(u.z); xwv[g][3] = bf2f(u.w);
    }

    f32x4 acc[2][2];
    #pragma unroll
    for (int mt = 0; mt < 2; ++mt)
      #pragma unroll
      for (int nt = 0; nt < 2; ++nt) acc[mt][nt] = f32x4{0.f, 0.f, 0.f, 0.f};

    if (t > 0) {
      const unsigned short* Aprev = hpp + (size_t)((t - 1) & 1) * (BATCH * HDIM);
      const unsigned short* hb0 = Aprev + (size_t)(r0 + (lane & 15)) * HDIM + quad * 8;
      const unsigned short* hb1 = hb0 + 16 * HDIM;
      #pragma unroll
      for (int j = 0; j < 32; ++j) {
        bf16x8 a0 = load_frag_l2(hb0 + j * 32);
        bf16x8 a1 = load_frag_l2(hb1 + j * 32);
        acc[0][0] = __builtin_amdgcn_mfma_f32_16x16x32_bf16(a0, whh[0][j], acc[0][0], 0, 0, 0);
        acc[0][1] = __builtin_amdgcn_mfma_f32_16x16x32_bf16(a0, whh[1][j], acc[0][1], 0, 0, 0);
        acc[1][0] = __builtin_amdgcn_mfma_f32_16x16x32_bf16(a1, whh[0][j], acc[1][0], 0, 0, 0);
        acc[1][1] = __builtin_amdgcn_mfma_f32_16x16x32_bf16(a1, whh[1][j], acc[1][1], 0, 0, 0);
      }
    }

    __syncthreads();
    #pragma unroll
    for (int mt = 0; mt < 2; ++mt)
      #pragma unroll
      for (int nt = 0; nt < 2; ++nt) {
        int hl = nt * 16 + (lane & 15);
        int rq = mt * 16 + quad * 4;
        *(f32x4*)&gbuf[wv][hl][rq] = acc[mt][nt];
      }
    __syncthreads();

    unsigned short* hdst = hpp + (size_t)(t & 1) * (BATCH * HDIM);
    #pragma unroll
    for (int r = 0; r < 4; ++r) {
      int row = rg * 4 + r;
      float gi = gbuf[0][hcl][row] + xwv[0][r] + bias[0];
      float gf = gbuf[1][hcl][row] + xwv[1][r] + bias[1];
      float gg = gbuf[2][hcl][row] + xwv[2][r] + bias[2];
      float go = gbuf[3][hcl][row] + xwv[3][r] + bias[3];
      float iv = sigm(gi), fv = sigm(gf), gv = tanh_f(gg), ov = sigm(go);
      float cn = fv * c[r] + iv * gv;
      c[r] = cn;
      float hv = ov * tanh_f(cn);
      int gidx = (r0 + row) * HDIM + hc0 + hcl;
      hdst[gidx] = f2bf(hv);
      if (h1t0 != nullptr && t == 0) h1t0[gidx] = f2bf(hv);
      if (t == tend - 1) cstate[gidx] = cn;
      if (t == T_STEPS - 1) { dout_h[gidx] = hv; dout_c[gidx] = cn; }
    }

    if (t != tend - 1)
      grp_barrier(gbar, gen_base + 2u + (unsigned int)(t - t0), !fast);
  }
}

__global__ void y_kernel(const unsigned short* __restrict__ h1t0,
                         const unsigned short* __restrict__ wlin,
                         const float* __restrict__ blin,
                         float* __restrict__ y)
{
  int b = blockIdx.x;
  int f = threadIdx.x;
  const ushort8v* hp = (const ushort8v*)(h1t0 + (size_t)b * HDIM);
  const ushort8v* wp = (const ushort8v*)(wlin + (size_t)f * HDIM);
  float acc = 0.f;
  for (int i = 0; i < HDIM / 8; ++i) {
    ushort8v hv = hp[i], wvv = wp[i];
    #pragma unroll
    for (int j = 0; j < 8; ++j) acc += bf2f(hv[j]) * bf2f(wvv[j]);
  }
  y[b * FDIM + f] = acc + blin[f];
}

// ---------------------------------------------------------------------------
extern "C" void kernel_launch(void* const* d_in, const int* in_sizes, int n_in,
                              void* d_out, int out_size, void* d_ws, size_t ws_size,
                              hipStream_t stream) {
  (void)in_sizes; (void)n_in; (void)out_size;
  const float* x    = (const float*)d_in[0];
  const float* Wih0 = (const float*)d_in[1];
  const float* Whh0 = (const float*)d_in[2];
  const float* bih0 = (const float*)d_in[3];
  const float* bhh0 = (const float*)d_in[4];
  const float* Wih1 = (const float*)d_in[5];
  const float* Whh1 = (const float*)d_in[6];
  const float* bih1 = (const float*)d_in[7];
  const float* bhh1 = (const float*)d_in[8];
  const float* Wlin = (const float*)d_in[9];
  const float* blin = (const float*)d_in[10];
  float* out = (float*)d_out;

  const size_t SZ_BAR   = 4096;
  const size_t SZ_PROBE = 32768;
  const size_t SZ_XBF   = (size_t)T_STEPS * BATCH * FDIM * 2;
  const size_t SZ_WIH1  = (size_t)GDIM * HDIM * 2;
  const size_t SZ_WLIN  = (size_t)FDIM * HDIM * 2;
  const size_t SZ_HPP   = (size_t)2 * BATCH * HDIM * 2;
  const size_t SZ_H1T0  = (size_t)BATCH * HDIM * 2;
  const size_t SZ_CST   = (size_t)BATCH * HDIM * 4;
  const size_t SLOT     = (size_t)BATCH * HDIM * 2;
  const size_t fixed = SZ_BAR + SZ_PROBE + SZ_XBF + SZ_WIH1 + SZ_WLIN + SZ_HPP + SZ_H1T0 + 2 * SZ_CST;

  int CH = 0;
  const int cands[5] = {64, 32, 16, 8, 4};
  for (int i = 0; i < 5; ++i) {
    int c = cands[i];
    size_t need = fixed + (size_t)(c + 1) * SLOT + (size_t)c * GDIM * BATCH * 2;
    if (need <= ws_size) { CH = c; break; }
  }
  if (CH == 0) {
    float v = 1.0e6f + (float)(ws_size >> 20);
    diag_kernel<<<(32768 + 255) / 256, 256, 0, stream>>>(out, 32768, v);
    return;
  }

  char* ws = (char*)d_ws;
  size_t o = 0;
  unsigned int*   bar   = (unsigned int*)(ws + o);    o += SZ_BAR;
  unsigned int*   probe = (unsigned int*)(ws + o);    o += SZ_PROBE;
  unsigned short* xbf   = (unsigned short*)(ws + o);  o += SZ_XBF;
  unsigned short* wih1b = (unsigned short*)(ws + o);  o += SZ_WIH1;
  unsigned short* wlinb = (unsigned short*)(ws + o);  o += SZ_WLIN;
  unsigned short* h1pp  = (unsigned short*)(ws + o);  o += SZ_HPP;
  unsigned short* h1t0  = (unsigned short*)(ws + o);  o += SZ_H1T0;
  float*          c0st  = (float*)(ws + o);           o += SZ_CST;
  float*          c1st  = (float*)(ws + o);           o += SZ_CST;
  unsigned short* slab  = (unsigned short*)(ws + o);  o += (size_t)(CH + 1) * SLOT;
  unsigned short* xw1   = (unsigned short*)(ws + o);  o += (size_t)CH * GDIM * BATCH * 2;

  hipMemsetAsync(bar, 0, SZ_BAR, stream);

  conv_bf16<<<(T_STEPS * BATCH * FDIM + 255) / 256, 256, 0, stream>>>(x, xbf, T_STEPS * BATCH * FDIM);
  conv_bf16<<<(GDIM * HDIM + 255) / 256, 256, 0, stream>>>(Wih1, wih1b, GDIM * HDIM);
  conv_bf16<<<(FDIM * HDIM + 255) / 256, 256, 0, stream>>>(Wlin, wlinb, FDIM * HDIM);

  float* hn0 = out + 32768;
  float* hn1 = out + 32768 + 262144;
  float* cn0 = out + 32768 + 524288;
  float* cn1 = out + 32768 + 524288 + 262144;

  unsigned int gen_base = 0;
  for (int ch = 0; ch < T_STEPS / CH; ++ch) {
    int t0 = ch * CH;
    lstm_layer0_kernel<<<256, 256, 0, stream>>>(
        xbf, Wih0, Whh0, bih0, bhh0, slab, c0st, t0, CH, gen_base, hn0, cn0, bar, probe);
    gen_base += (unsigned int)CH;   // 1 probe + (CH-1) step barriers
    gemm_bt_xw<<<dim3(CH * 2, 32), 256, 0, stream>>>(
        slab + BATCH * HDIM, wih1b, xw1, HDIM);
    lstm_layer1_kernel<<<256, 256, 0, stream>>>(
        xw1, Whh1, bih1, bhh1, h1pp, c1st, t0, CH, gen_base, h1t0, hn1, cn1, bar, probe);
    gen_base += (unsigned int)CH;
  }

  y_kernel<<<256, 128, 0, stream>>>(h1t0, wlinb, blin, out);
}

// Round 6
// 5996.508 us; speedup vs baseline: 1.8017x; 1.8017x over previous
//
#include <hip/hip_runtime.h>
#include <stdint.h>

// ---------------------------------------------------------------------------
// 2-layer LSTM (T=256, B=256, F=128, H=1024) for MI355X (gfx950).
// R6: R4 structure (LDS h-slab staging, per-group 32-WG monotonic barriers)
// with the agent fence pair (wbl2 + inv-L2, two 4MB tag walks per step)
// replaced by a vL1-only invalidate (`buffer_inv`, 32KB per-CU) in the fast
// path. Valid because h-sharing is strictly intra-mi-group and same-mi WGs
// are co-XCD under round-robin dispatch: producer stores drain write-through
// to the shared XCD L2 at vmcnt(0); consumer only needs its vL1 dropped.
// A per-dispatch probe verifies co-XCD visibility (d_ws 0xAA re-poison makes
// false-pass impossible); on failure -> R4 heavy agent fences (correct, slow).
// ---------------------------------------------------------------------------

typedef __bf16 bf16x8 __attribute__((ext_vector_type(8)));
typedef float  f32x4  __attribute__((ext_vector_type(4)));
typedef unsigned short ushort8v __attribute__((ext_vector_type(8)));
typedef unsigned short ushort4v __attribute__((ext_vector_type(4)));
typedef unsigned int   uint4v   __attribute__((ext_vector_type(4)));
typedef __attribute__((address_space(1))) unsigned int as1_u32;
typedef __attribute__((address_space(3))) unsigned int as3_u32;

#define T_STEPS 256
#define BATCH   256
#define HDIM    1024
#define GDIM    4096
#define FDIM    128
#define AS_STRIDE 2080   // bytes/row in LDS h slab (R3 layout: ~1% conflict cost)

static __device__ __forceinline__ float bf2f(unsigned short u) {
  union { unsigned int i; float f; } v; v.i = ((unsigned int)u) << 16; return v.f;
}
static __device__ __forceinline__ unsigned short f2bf(float f) {
  return __builtin_bit_cast(unsigned short, (__bf16)f);
}
static __device__ __forceinline__ float sigm(float x) { return 1.f / (1.f + __expf(-x)); }
static __device__ __forceinline__ float tanh_f(float x) { return 2.f / (1.f + __expf(-2.f * x)) - 1.f; }

// Invalidate this CU's vector L1 (32KB). Much cheaper than agent acquire
// (which invalidates the 4MB XCD L2). gfx940+ mnemonic.
static __device__ __forceinline__ void vl1_inv() {
  asm volatile("buffer_inv" ::: "memory");
}

__global__ void conv_bf16(const float* __restrict__ s, unsigned short* __restrict__ d, int n) {
  int i = blockIdx.x * 256 + threadIdx.x;
  if (i < n) d[i] = f2bf(s[i]);
}

__global__ void diag_kernel(float* out, int n, float v) {
  int i = blockIdx.x * 256 + threadIdx.x;
  if (i < n) out[i] = v;
}

// ---------------- per-group (32-WG, same mi) monotonic barrier ---------------
// gbar: this group's 256B region. [0]=arrival count, [32]=generation.
// fast: no fences; caller relies on vmcnt(0) drain (syncthreads) + vL1 inv
//       after wake (done here, by every wave, so each wave's later loads miss
//       vL1 and hit the shared XCD L2).
// heavy: agent release/acquire fences (cross-XCD-safe fallback, R4 behavior).
__device__ __forceinline__ void grp_barrier(unsigned int* gbar, unsigned int target, bool fast) {
  __syncthreads();   // drains vmcnt(0): all WG stores visible at L2
  if (threadIdx.x == 0) {
    if (!fast) __builtin_amdgcn_fence(__ATOMIC_RELEASE, "agent");
    unsigned int my = __hip_atomic_fetch_add(&gbar[0], 1u, __ATOMIC_RELAXED, __HIP_MEMORY_SCOPE_AGENT);
    if ((my & 31u) == 31u)
      __hip_atomic_fetch_add(&gbar[32], 1u, __ATOMIC_RELAXED, __HIP_MEMORY_SCOPE_AGENT);
    for (unsigned int it = 0; it < (1u << 14); ++it) {
      unsigned int g = __hip_atomic_load(&gbar[32], __ATOMIC_RELAXED, __HIP_MEMORY_SCOPE_AGENT);
      if ((int)(g - target) >= 0) break;
      __builtin_amdgcn_s_sleep(1);
    }
    if (!fast) __builtin_amdgcn_fence(__ATOMIC_ACQUIRE, "agent");
  }
  __syncthreads();
  if (fast) vl1_inv();   // every wave: drop stale vL1 lines before h reads
}

// --------------------------- gemm_bt: C = A @ B^T ---------------------------
// A: (M,K) bf16 row-major. B: (4096,K) bf16. global_load_lds width-16 staging.
// Output alt layout xw[(t_local*4096 + n)*256 + b], m = t_local*256 + b.
__global__ __launch_bounds__(256) void gemm_bt_xw(
    const unsigned short* __restrict__ A,
    const unsigned short* __restrict__ B,
    unsigned short* __restrict__ xw,
    int K)
{
  const int tid = threadIdx.x, lane = tid & 63, w = tid >> 6;
  const int m0 = blockIdx.x * 128;
  const int n0 = blockIdx.y * 128;
  __shared__ unsigned short As[128 * 64];
  __shared__ unsigned short Bs[128 * 64];
  const int mrow0 = (w & 1) * 64, ncol0 = (w >> 1) * 64;
  const int quad = lane >> 4;

  f32x4 acc[4][4];
  #pragma unroll
  for (int i = 0; i < 4; ++i)
    #pragma unroll
    for (int j = 0; j < 4; ++j) acc[i][j] = f32x4{0.f, 0.f, 0.f, 0.f};

  const int kiter = K >> 6;
  for (int ki = 0; ki < kiter; ++ki) {
    const int k0 = ki * 64;
    __syncthreads();
    #pragma unroll
    for (int i = 0; i < 4; ++i) {
      int obase = (w * 4 + i) * 1024;          // wave-uniform LDS byte base
      int o = obase + lane * 16;
      int row = o >> 7; int kb = o & 127;
      const char* ga = (const char*)A + ((size_t)(m0 + row) * K + k0) * 2 + kb;
      const char* gb = (const char*)B + ((size_t)(n0 + row) * K + k0) * 2 + kb;
      __builtin_amdgcn_global_load_lds((const as1_u32*)ga, (as3_u32*)((char*)As + obase), 16, 0, 0);
      __builtin_amdgcn_global_load_lds((const as1_u32*)gb, (as3_u32*)((char*)Bs + obase), 16, 0, 0);
    }
    __syncthreads();
    #pragma unroll
    for (int kk = 0; kk < 2; ++kk) {
      bf16x8 af[4], bfr[4];
      #pragma unroll
      for (int mt = 0; mt < 4; ++mt)
        af[mt] = *(const bf16x8*)(As + (mrow0 + mt * 16 + (lane & 15)) * 64 + kk * 32 + quad * 8);
      #pragma unroll
      for (int nt = 0; nt < 4; ++nt)
        bfr[nt] = *(const bf16x8*)(Bs + (ncol0 + nt * 16 + (lane & 15)) * 64 + kk * 32 + quad * 8);
      #pragma unroll
      for (int mt = 0; mt < 4; ++mt)
        #pragma unroll
        for (int nt = 0; nt < 4; ++nt)
          acc[mt][nt] = __builtin_amdgcn_mfma_f32_16x16x32_bf16(af[mt], bfr[nt], acc[mt][nt], 0, 0, 0);
    }
  }
  #pragma unroll
  for (int mt = 0; mt < 4; ++mt) {
    int m = m0 + mrow0 + mt * 16 + quad * 4;
    int tl = m >> 8, b = m & 255;
    #pragma unroll
    for (int nt = 0; nt < 4; ++nt) {
      int col = n0 + ncol0 + nt * 16 + (lane & 15);
      ushort4v v;
      v.x = f2bf(acc[mt][nt][0]); v.y = f2bf(acc[mt][nt][1]);
      v.z = f2bf(acc[mt][nt][2]); v.w = f2bf(acc[mt][nt][3]);
      *(ushort4v*)(xw + ((size_t)tl * GDIM + col) * BATCH + b) = v;
    }
  }
}

// ---------------- probe: validate intra-XCD visibility for this group --------
// Plain store -> fast barrier -> vL1 inv -> plain reads of all 32 members.
// If any token stale (group not co-XCD at L2), use heavy fences all launch.
// d_ws is re-poisoned 0xAA before every launch, so LLC can never hold the
// current salt for a line whose fresh copy is dirty in another XCD's L2.
__device__ __forceinline__ bool probe_fast(unsigned int* probe, unsigned int* gbar,
                                           unsigned int salt, unsigned int target,
                                           unsigned int* flagLds) {
  const int wg = blockIdx.x, mi = wg & 7;
  if (threadIdx.x == 0) probe[wg * 32] = salt ^ (unsigned int)wg;
  grp_barrier(gbar, target, true);   // fast barrier + vL1 inv
  if (threadIdx.x == 0) {
    unsigned int bad = 0;
    for (int k = 0; k < 32; ++k) {
      int member = mi + 8 * k;
      unsigned int v = probe[member * 32];
      if (v != (salt ^ (unsigned int)member)) bad = 1;
    }
    *flagLds = bad;
  }
  __syncthreads();
  return (*flagLds == 0);
}

// --------------------------- layer 0: fused persistent chunk -----------------
// 256 WGs x 256 thr, 1/CU. WG (mi=wg&7, ni=wg>>3): rows [32mi,+32), cols [32ni,+32).
// Wave g = gate g; W_hh0 + W_ih0 B-fragments resident in VGPRs.
__global__ __launch_bounds__(256, 1) void lstm_layer0_kernel(
    const unsigned short* __restrict__ xbf,  // (T,B,F) bf16
    const float* __restrict__ Wih,           // (4096,128) fp32
    const float* __restrict__ Whh,           // (4096,1024) fp32
    const float* __restrict__ bih,
    const float* __restrict__ bhh,
    unsigned short* __restrict__ slab,       // (ch_len+1, B, H) bf16
    float* __restrict__ cstate,              // (B,H) fp32
    int t0, int ch_len, unsigned int gen_base,
    float* __restrict__ dout_h,
    float* __restrict__ dout_c,
    unsigned int* __restrict__ bar,
    unsigned int* __restrict__ probe)
{
  const int tid = threadIdx.x, lane = tid & 63, wv = tid >> 6;
  const int quad = lane >> 4;
  const int wg = blockIdx.x;
  const int mi = wg & 7, ni = wg >> 3;
  const int r0 = mi * 32, hc0 = ni * 32;
  unsigned int* gbar = bar + mi * 64;   // 256B per group

  __shared__ unsigned short As[32 * (AS_STRIDE / 2)];
  __shared__ float gbuf[4][32][36];
  __shared__ unsigned int flagLds;

  bf16x8 whh[2][32];
  #pragma unroll
  for (int nt = 0; nt < 2; ++nt) {
    const float* wrow = Whh + (size_t)(wv * HDIM + hc0 + nt * 16 + (lane & 15)) * HDIM + quad * 8;
    #pragma unroll
    for (int kk = 0; kk < 32; ++kk) {
      f32x4 f0 = *(const f32x4*)(wrow + kk * 32);
      f32x4 f1 = *(const f32x4*)(wrow + kk * 32 + 4);
      bf16x8 r;
      r[0] = (__bf16)f0[0]; r[1] = (__bf16)f0[1]; r[2] = (__bf16)f0[2]; r[3] = (__bf16)f0[3];
      r[4] = (__bf16)f1[0]; r[5] = (__bf16)f1[1]; r[6] = (__bf16)f1[2]; r[7] = (__bf16)f1[3];
      whh[nt][kk] = r;
    }
  }
  bf16x8 wih[2][4];
  #pragma unroll
  for (int nt = 0; nt < 2; ++nt) {
    const float* wrow = Wih + (size_t)(wv * HDIM + hc0 + nt * 16 + (lane & 15)) * FDIM + quad * 8;
    #pragma unroll
    for (int kk = 0; kk < 4; ++kk) {
      f32x4 f0 = *(const f32x4*)(wrow + kk * 32);
      f32x4 f1 = *(const f32x4*)(wrow + kk * 32 + 4);
      bf16x8 r;
      r[0] = (__bf16)f0[0]; r[1] = (__bf16)f0[1]; r[2] = (__bf16)f0[2]; r[3] = (__bf16)f0[3];
      r[4] = (__bf16)f1[0]; r[5] = (__bf16)f1[1]; r[6] = (__bf16)f1[2]; r[7] = (__bf16)f1[3];
      wih[nt][kk] = r;
    }
  }

  const int hcl = tid & 31, rg = tid >> 5;
  float bias[4];
  #pragma unroll
  for (int g = 0; g < 4; ++g)
    bias[g] = bih[g * HDIM + hc0 + hcl] + bhh[g * HDIM + hc0 + hcl];

  float c[4];
  #pragma unroll
  for (int r = 0; r < 4; ++r)
    c[r] = (t0 == 0) ? 0.f : cstate[(size_t)(r0 + rg * 4 + r) * HDIM + hc0 + hcl];

  unsigned int salt = 0x9E3779B9u ^ (gen_base * 2654435761u);
  bool fast = probe_fast(probe, gbar, salt, gen_base + 1u, &flagLds);

  const int tend = t0 + ch_len;
  #pragma unroll 1
  for (int t = t0; t < tend; ++t) {
    f32x4 acc[2][2];
    #pragma unroll
    for (int mt = 0; mt < 2; ++mt)
      #pragma unroll
      for (int nt = 0; nt < 2; ++nt) acc[mt][nt] = f32x4{0.f, 0.f, 0.f, 0.f};

    // x projection (K=128), read-only input
    #pragma unroll
    for (int j = 0; j < 4; ++j) {
      bf16x8 af[2];
      #pragma unroll
      for (int mt = 0; mt < 2; ++mt)
        af[mt] = *(const bf16x8*)(xbf + (size_t)(t * BATCH + r0 + mt * 16 + (lane & 15)) * FDIM + j * 32 + quad * 8);
      #pragma unroll
      for (int mt = 0; mt < 2; ++mt)
        #pragma unroll
        for (int nt = 0; nt < 2; ++nt)
          acc[mt][nt] = __builtin_amdgcn_mfma_f32_16x16x32_bf16(af[mt], wih[nt][j], acc[mt][nt], 0, 0, 0);
    }

    if (t > 0) {
      const unsigned short* Aprev = slab + (size_t)(t - t0) * (BATCH * HDIM);
      // cooperative stage: 32 rows x 1024 cols (64KB) via plain dwordx4
      #pragma unroll
      for (int p = 0; p < 16; ++p) {
        int idx = p * 256 + tid;
        int row = idx >> 7, gc = idx & 127;
        *(uint4v*)((char*)As + row * AS_STRIDE + gc * 16) =
            *(const uint4v*)(Aprev + (size_t)(r0 + row) * HDIM + gc * 8);
      }
      __syncthreads();
      #pragma unroll
      for (int j = 0; j < 32; ++j) {
        bf16x8 af[2];
        #pragma unroll
        for (int mt = 0; mt < 2; ++mt)
          af[mt] = *(const bf16x8*)((const char*)As + (mt * 16 + (lane & 15)) * AS_STRIDE + j * 64 + quad * 16);
        #pragma unroll
        for (int mt = 0; mt < 2; ++mt)
          #pragma unroll
          for (int nt = 0; nt < 2; ++nt)
            acc[mt][nt] = __builtin_amdgcn_mfma_f32_16x16x32_bf16(af[mt], whh[nt][j], acc[mt][nt], 0, 0, 0);
      }
    }

    __syncthreads();
    #pragma unroll
    for (int mt = 0; mt < 2; ++mt)
      #pragma unroll
      for (int nt = 0; nt < 2; ++nt) {
        int hl = nt * 16 + (lane & 15);
        int rq = mt * 16 + quad * 4;
        *(f32x4*)&gbuf[wv][hl][rq] = acc[mt][nt];
      }
    __syncthreads();

    unsigned short* hdst = slab + (size_t)(t - t0 + 1) * (BATCH * HDIM);
    unsigned short* hdst0 = slab;
    #pragma unroll
    for (int r = 0; r < 4; ++r) {
      int row = rg * 4 + r;
      float gi = gbuf[0][hcl][row] + bias[0];
      float gf = gbuf[1][hcl][row] + bias[1];
      float gg = gbuf[2][hcl][row] + bias[2];
      float go = gbuf[3][hcl][row] + bias[3];
      float iv = sigm(gi), fv = sigm(gf), gv = tanh_f(gg), ov = sigm(go);
      float cn = fv * c[r] + iv * gv;
      c[r] = cn;
      float hv = ov * tanh_f(cn);
      int gidx = (r0 + row) * HDIM + hc0 + hcl;
      unsigned short hb = f2bf(hv);
      hdst[gidx] = hb;
      if (t == tend - 1) { hdst0[gidx] = hb; cstate[gidx] = cn; }
      if (t == T_STEPS - 1) { dout_h[gidx] = hv; dout_c[gidx] = cn; }
    }

    if (t != tend - 1)
      grp_barrier(gbar, gen_base + 2u + (unsigned int)(t - t0), fast);
  }
}

// --------------------------- layer 1: persistent chunk ----------------------
__global__ __launch_bounds__(256, 1) void lstm_layer1_kernel(
    const unsigned short* __restrict__ xw,   // (ch_len, 4096, 256) bf16
    const float* __restrict__ Whh,
    const float* __restrict__ bih,
    const float* __restrict__ bhh,
    unsigned short* __restrict__ hpp,        // 2-slot ping-pong
    float* __restrict__ cstate,
    int t0, int ch_len, unsigned int gen_base,
    unsigned short* __restrict__ h1t0,
    float* __restrict__ dout_h,
    float* __restrict__ dout_c,
    unsigned int* __restrict__ bar,
    unsigned int* __restrict__ probe)
{
  const int tid = threadIdx.x, lane = tid & 63, wv = tid >> 6;
  const int quad = lane >> 4;
  const int wg = blockIdx.x;
  const int mi = wg & 7, ni = wg >> 3;
  const int r0 = mi * 32, hc0 = ni * 32;
  unsigned int* gbar = bar + mi * 64;

  __shared__ unsigned short As[32 * (AS_STRIDE / 2)];
  __shared__ float gbuf[4][32][36];
  __shared__ unsigned int flagLds;

  bf16x8 whh[2][32];
  #pragma unroll
  for (int nt = 0; nt < 2; ++nt) {
    const float* wrow = Whh + (size_t)(wv * HDIM + hc0 + nt * 16 + (lane & 15)) * HDIM + quad * 8;
    #pragma unroll
    for (int kk = 0; kk < 32; ++kk) {
      f32x4 f0 = *(const f32x4*)(wrow + kk * 32);
      f32x4 f1 = *(const f32x4*)(wrow + kk * 32 + 4);
      bf16x8 r;
      r[0] = (__bf16)f0[0]; r[1] = (__bf16)f0[1]; r[2] = (__bf16)f0[2]; r[3] = (__bf16)f0[3];
      r[4] = (__bf16)f1[0]; r[5] = (__bf16)f1[1]; r[6] = (__bf16)f1[2]; r[7] = (__bf16)f1[3];
      whh[nt][kk] = r;
    }
  }

  const int hcl = tid & 31, rg = tid >> 5;
  float bias[4];
  #pragma unroll
  for (int g = 0; g < 4; ++g)
    bias[g] = bih[g * HDIM + hc0 + hcl] + bhh[g * HDIM + hc0 + hcl];

  float c[4];
  #pragma unroll
  for (int r = 0; r < 4; ++r)
    c[r] = (t0 == 0) ? 0.f : cstate[(size_t)(r0 + rg * 4 + r) * HDIM + hc0 + hcl];

  unsigned int salt = 0xB5297A4Du ^ (gen_base * 2654435761u);
  bool fast = probe_fast(probe, gbar, salt, gen_base + 1u, &flagLds);

  const int tend = t0 + ch_len;
  #pragma unroll 1
  for (int t = t0; t < tend; ++t) {
    // hoisted xw loads (independent of h)
    float xwv[4][4];
    #pragma unroll
    for (int g = 0; g < 4; ++g) {
      const unsigned short* xp =
          xw + ((size_t)(t - t0) * GDIM + g * HDIM + hc0 + hcl) * BATCH + r0 + rg * 4;
      ushort4v u = *(const ushort4v*)xp;
      xwv[g][0] = bf2f(u.x); xwv[g][1] = bf2f(u.y);
      xwv[g][2] = bf2f(u.z); xwv[g][3] = bf2f(u.w);
    }

    f32x4 acc[2][2];
    #pragma unroll
    for (int mt = 0; mt < 2; ++mt)
      #pragma unroll
      for (int nt = 0; nt < 2; ++nt) acc[mt][nt] = f32x4{0.f, 0.f, 0.f, 0.f};

    if (t > 0) {
      const unsigned short* Aprev = hpp + (size_t)((t - 1) & 1) * (BATCH * HDIM);
      #pragma unroll
      for (int p = 0; p < 16; ++p) {
        int idx = p * 256 + tid;
        int row = idx >> 7, gc = idx & 127;
        *(uint4v*)((char*)As + row * AS_STRIDE + gc * 16) =
            *(const uint4v*)(Aprev + (size_t)(r0 + row) * HDIM + gc * 8);
      }
      __syncthreads();
      #pragma unroll
      for (int j = 0; j < 32; ++j) {
        bf16x8 af[2];
        #pragma unroll
        for (int mt = 0; mt < 2; ++mt)
          af[mt] = *(const bf16x8*)((const char*)As + (mt * 16 + (lane & 15)) * AS_STRIDE + j * 64 + quad * 16);
        #pragma unroll
        for (int mt = 0; mt < 2; ++mt)
          #pragma unroll
          for (int nt = 0; nt < 2; ++nt)
            acc[mt][nt] = __builtin_amdgcn_mfma_f32_16x16x32_bf16(af[mt], whh[nt][j], acc[mt][nt], 0, 0, 0);
      }
    }

    __syncthreads();
    #pragma unroll
    for (int mt = 0; mt < 2; ++mt)
      #pragma unroll
      for (int nt = 0; nt < 2; ++nt) {
        int hl = nt * 16 + (lane & 15);
        int rq = mt * 16 + quad * 4;
        *(f32x4*)&gbuf[wv][hl][rq] = acc[mt][nt];
      }
    __syncthreads();

    unsigned short* hdst = hpp + (size_t)(t & 1) * (BATCH * HDIM);
    #pragma unroll
    for (int r = 0; r < 4; ++r) {
      int row = rg * 4 + r;
      float gi = gbuf[0][hcl][row] + xwv[0][r] + bias[0];
      float gf = gbuf[1][hcl][row] + xwv[1][r] + bias[1];
      float gg = gbuf[2][hcl][row] + xwv[2][r] + bias[2];
      float go = gbuf[3][hcl][row] + xwv[3][r] + bias[3];
      float iv = sigm(gi), fv = sigm(gf), gv = tanh_f(gg), ov = sigm(go);
      float cn = fv * c[r] + iv * gv;
      c[r] = cn;
      float hv = ov * tanh_f(cn);
      int gidx = (r0 + row) * HDIM + hc0 + hcl;
      hdst[gidx] = f2bf(hv);
      if (h1t0 != nullptr && t == 0) h1t0[gidx] = f2bf(hv);
      if (t == tend - 1) cstate[gidx] = cn;
      if (t == T_STEPS - 1) { dout_h[gidx] = hv; dout_c[gidx] = cn; }
    }

    if (t != tend - 1)
      grp_barrier(gbar, gen_base + 2u + (unsigned int)(t - t0), fast);
  }
}

__global__ void y_kernel(const unsigned short* __restrict__ h1t0,
                         const unsigned short* __restrict__ wlin,
                         const float* __restrict__ blin,
                         float* __restrict__ y)
{
  int b = blockIdx.x;
  int f = threadIdx.x;
  const ushort8v* hp = (const ushort8v*)(h1t0 + (size_t)b * HDIM);
  const ushort8v* wp = (const ushort8v*)(wlin + (size_t)f * HDIM);
  float acc = 0.f;
  for (int i = 0; i < HDIM / 8; ++i) {
    ushort8v hv = hp[i], wvv = wp[i];
    #pragma unroll
    for (int j = 0; j < 8; ++j) acc += bf2f(hv[j]) * bf2f(wvv[j]);
  }
  y[b * FDIM + f] = acc + blin[f];
}

// ---------------------------------------------------------------------------
extern "C" void kernel_launch(void* const* d_in, const int* in_sizes, int n_in,
                              void* d_out, int out_size, void* d_ws, size_t ws_size,
                              hipStream_t stream) {
  (void)in_sizes; (void)n_in; (void)out_size;
  const float* x    = (const float*)d_in[0];
  const float* Wih0 = (const float*)d_in[1];
  const float* Whh0 = (const float*)d_in[2];
  const float* bih0 = (const float*)d_in[3];
  const float* bhh0 = (const float*)d_in[4];
  const float* Wih1 = (const float*)d_in[5];
  const float* Whh1 = (const float*)d_in[6];
  const float* bih1 = (const float*)d_in[7];
  const float* bhh1 = (const float*)d_in[8];
  const float* Wlin = (const float*)d_in[9];
  const float* blin = (const float*)d_in[10];
  float* out = (float*)d_out;

  const size_t SZ_BAR   = 4096;
  const size_t SZ_PROBE = 32768;
  const size_t SZ_XBF   = (size_t)T_STEPS * BATCH * FDIM * 2;
  const size_t SZ_WIH1  = (size_t)GDIM * HDIM * 2;
  const size_t SZ_WLIN  = (size_t)FDIM * HDIM * 2;
  const size_t SZ_HPP   = (size_t)2 * BATCH * HDIM * 2;
  const size_t SZ_H1T0  = (size_t)BATCH * HDIM * 2;
  const size_t SZ_CST   = (size_t)BATCH * HDIM * 4;
  const size_t SLOT     = (size_t)BATCH * HDIM * 2;
  const size_t fixed = SZ_BAR + SZ_PROBE + SZ_XBF + SZ_WIH1 + SZ_WLIN + SZ_HPP + SZ_H1T0 + 2 * SZ_CST;

  int CH = 0;
  const int cands[5] = {64, 32, 16, 8, 4};
  for (int i = 0; i < 5; ++i) {
    int c = cands[i];
    size_t need = fixed + (size_t)(c + 1) * SLOT + (size_t)c * GDIM * BATCH * 2;
    if (need <= ws_size) { CH = c; break; }
  }
  if (CH == 0) {
    float v = 1.0e6f + (float)(ws_size >> 20);
    diag_kernel<<<(32768 + 255) / 256, 256, 0, stream>>>(out, 32768, v);
    return;
  }

  char* ws = (char*)d_ws;
  size_t o = 0;
  unsigned int*   bar   = (unsigned int*)(ws + o);    o += SZ_BAR;
  unsigned int*   probe = (unsigned int*)(ws + o);    o += SZ_PROBE;
  unsigned short* xbf   = (unsigned short*)(ws + o);  o += SZ_XBF;
  unsigned short* wih1b = (unsigned short*)(ws + o);  o += SZ_WIH1;
  unsigned short* wlinb = (unsigned short*)(ws + o);  o += SZ_WLIN;
  unsigned short* h1pp  = (unsigned short*)(ws + o);  o += SZ_HPP;
  unsigned short* h1t0  = (unsigned short*)(ws + o);  o += SZ_H1T0;
  float*          c0st  = (float*)(ws + o);           o += SZ_CST;
  float*          c1st  = (float*)(ws + o);           o += SZ_CST;
  unsigned short* slab  = (unsigned short*)(ws + o);  o += (size_t)(CH + 1) * SLOT;
  unsigned short* xw1   = (unsigned short*)(ws + o);  o += (size_t)CH * GDIM * BATCH * 2;

  hipMemsetAsync(bar, 0, SZ_BAR, stream);

  conv_bf16<<<(T_STEPS * BATCH * FDIM + 255) / 256, 256, 0, stream>>>(x, xbf, T_STEPS * BATCH * FDIM);
  conv_bf16<<<(GDIM * HDIM + 255) / 256, 256, 0, stream>>>(Wih1, wih1b, GDIM * HDIM);
  conv_bf16<<<(FDIM * HDIM + 255) / 256, 256, 0, stream>>>(Wlin, wlinb, FDIM * HDIM);

  float* hn0 = out + 32768;
  float* hn1 = out + 32768 + 262144;
  float* cn0 = out + 32768 + 524288;
  float* cn1 = out + 32768 + 524288 + 262144;

  unsigned int gen_base = 0;
  for (int ch = 0; ch < T_STEPS / CH; ++ch) {
    int t0 = ch * CH;
    lstm_layer0_kernel<<<256, 256, 0, stream>>>(
        xbf, Wih0, Whh0, bih0, bhh0, slab, c0st, t0, CH, gen_base, hn0, cn0, bar, probe);
    gen_base += (unsigned int)CH;   // 1 probe + (CH-1) step barriers
    gemm_bt_xw<<<dim3(CH * 2, 32), 256, 0, stream>>>(
        slab + BATCH * HDIM, wih1b, xw1, HDIM);
    lstm_layer1_kernel<<<256, 256, 0, stream>>>(
        xw1, Whh1, bih1, bhh1, h1pp, c1st, t0, CH, gen_base, h1t0, hn1, cn1, bar, probe);
    gen_base += (unsigned int)CH;
  }

  y_kernel<<<256, 128, 0, stream>>>(h1t0, wlinb, blin, out);
}